// Round 12
// baseline (168.858 us; speedup 1.0000x reference)
//
#include <hip/hip_runtime.h>
#include <cmath>
#include <cstdint>

#define BATCH  256
#define TT     1024
#define FIN    16
#define LSZ    256
#define NCOH   32
#define TC     16
#define NCHUNK (TT / TC)          // 64
#define HBS    260                // s_hb f32 row stride
#define HCS    68                 // s_hc f32 row stride
#define YFS    324                // s_yf f32 row stride (320 used + pad)

typedef __attribute__((ext_vector_type(8))) short short8;
typedef __attribute__((ext_vector_type(4))) float floatx4;

__device__ __forceinline__ unsigned short f2bf_rne(float f) {
    union { float f; unsigned int i; } v; v.f = f;
    unsigned int b = v.i;
    return (unsigned short)((b + 0x7FFFu + ((b >> 16) & 1u)) >> 16);
}
__device__ __forceinline__ unsigned short f2bf_hu(float f) {  // round-half-up, 2 ops
    union { float f; unsigned int i; } v; v.f = f;
    return (unsigned short)((v.i + 0x8000u) >> 16);
}
__device__ __forceinline__ float u2f(unsigned int u) {
    union { unsigned int i; float f; } v; v.i = u; return v.f;
}
__device__ __forceinline__ void bfsplit(float v, unsigned short& hi, unsigned short& lo) {
    unsigned short h = f2bf_rne(v);
    lo = f2bf_rne(v - u2f((unsigned int)h << 16));
    hi = h;
}

// raw barrier: LDS-ordered only — global loads/stores stay in flight
#define BARRIER() asm volatile("s_waitcnt lgkmcnt(0)\n\ts_barrier" ::: "memory")

// Material constants (plane stress), rotated basis u=s0+s1, v=s0-s1
#define MCU    285.71428571428571f   // E/(1-nu)   : weight for u-columns
#define MCV    153.84615384615384f   // E/(1+nu)   : weight for v-columns
#define MC22   76.92307692307692f
#define MSY0   2.0f
#define AK     0.958466453674121406f  // 3G/(3G+H)
#define BK     0.041533546325878594f  // H/(3G+H)

__global__ __launch_bounds__(256, 1)
void fused_mat_kernel(const float* __restrict__ x,
                      const float* __restrict__ w1,
                      const float* __restrict__ w2,
                      float* __restrict__ out)
{
    __shared__ __attribute__((aligned(16))) float s_hb[2][TC][HBS];  // (du,dv,ds2) per chain
    __shared__ __attribute__((aligned(16))) float s_hc[2][TC][HCS];  // abs jumps
    __shared__ __attribute__((aligned(16))) float s_yf[2][TC][YFS];  // f32 y: (u,v,s2,0)*64 | (an,as)*32

    const int tid  = threadIdx.x;
    const int b    = blockIdx.x;
    const int lane = tid & 63;
    const int wv   = tid >> 6;    // 0: bulk, 1: cohesive, 2: h-GEMM, 3: out-GEMM
    const int m    = lane & 15;
    const int q    = lane >> 4;

    const size_t xrow = (size_t)b * TT;

    short8 w1fdh[12], w1fdl[12];  // wave 2: rotated C-folded W1 hi/lo (bulk cols)
    short8 w1f4[4];               // wave 2: plain W1 (cohesive cols)
    short8 vf[10];                // wave 3: rotated/scaled softplus(W2), permuted-k
    uint4  rxc[2], rxp[2];        // wave 2: raw x bits, cur/prev row

    if (wv == 2) {
        // rotated C-folded W1 fragments, bulk cols (n<12): value per (col=chain*3+comp)
        #pragma unroll
        for (int n = 0; n < 12; ++n) {
            #pragma unroll
            for (int j = 0; j < 8; ++j) {
                float v = 0.f;
                if (q < 2) {
                    const int l = n * 16 + m, c = l / 3, cm = l - 3 * c, f = q * 8 + j;
                    const float wa = w1[(3 * c + 0) * FIN + f];
                    const float wb = w1[(3 * c + 1) * FIN + f];
                    const float wc = w1[(3 * c + 2) * FIN + f];
                    v = (cm == 0) ? MCU * (wa + wb)
                      : (cm == 1) ? MCV * (wa - wb)
                                  : MC22 * wc;
                }
                unsigned short hi, lo;
                bfsplit(v, hi, lo);
                w1fdh[n][j] = (short)hi;
                w1fdl[n][j] = (short)lo;
            }
        }
        #pragma unroll
        for (int n = 12; n < 16; ++n) {
            #pragma unroll
            for (int j = 0; j < 8; ++j) {
                unsigned short v = 0;
                if (q < 2) v = f2bf_rne(w1[(n * 16 + m) * FIN + q * 8 + j]);
                w1f4[n - 12][j] = (short)v;
            }
        }
        // prologue: produce chunk 0
        {
            short8 ax, adh, adl;
            #pragma unroll
            for (int j = 0; j < 8; ++j) {
                float xc = 0.f, xp = 0.f;
                if (q < 2) {
                    xc = x[(xrow + m) * FIN + q * 8 + j];
                    if (m > 0) xp = x[(xrow + m - 1) * FIN + q * 8 + j];
                }
                unsigned short hi, lo;
                bfsplit(xc - xp, hi, lo);
                ax[j]  = (short)f2bf_rne(xc);
                adh[j] = (short)hi;
                adl[j] = (short)lo;
            }
            #pragma unroll
            for (int n = 0; n < 16; ++n) {
                floatx4 acc = {0.f, 0.f, 0.f, 0.f};
                if (n < 12) {
                    acc = __builtin_amdgcn_mfma_f32_16x16x32_bf16(adh, w1fdh[n], acc, 0, 0, 0);
                    acc = __builtin_amdgcn_mfma_f32_16x16x32_bf16(adl, w1fdh[n], acc, 0, 0, 0);
                    acc = __builtin_amdgcn_mfma_f32_16x16x32_bf16(adh, w1fdl[n], acc, 0, 0, 0);
                } else {
                    acc = __builtin_amdgcn_mfma_f32_16x16x32_bf16(ax, w1f4[n - 12], acc, 0, 0, 0);
                }
                const int col = n * 16 + m;
                if (n < 12) {
                    const int cc = col / 3, cm = col - cc * 3;
                    #pragma unroll
                    for (int r = 0; r < 4; ++r)
                        s_hb[0][q * 4 + r][cc * 4 + cm] = acc[r];
                } else {
                    #pragma unroll
                    for (int r = 0; r < 4; ++r)
                        s_hc[0][q * 4 + r][col - 192] = acc[r];
                }
            }
        }
        if (q < 2) {
            const int rowB = TC + m;
            const float* xc = x + (xrow + rowB) * FIN + q * 8;
            const float* xp = x + (xrow + rowB - 1) * FIN + q * 8;
            rxc[0] = *(const uint4*)xc;  rxc[1] = *(const uint4*)(xc + 4);
            rxp[0] = *(const uint4*)xp;  rxp[1] = *(const uint4*)(xp + 4);
        }
    } else if (wv == 3) {
        // vf: position p -> weight; bulk rotated (0.5*(V0±V1), V2), pad 0; coh 50*sp
        #pragma unroll
        for (int ks = 0; ks < 10; ++ks) {
            #pragma unroll
            for (int j = 0; j < 8; ++j) {
                const int p = ks * 32 + q * 8 + j;
                float v = 0.f;
                if (p < 256) {
                    const int comp = p & 3;
                    if (comp < 3) {
                        const int c = p >> 2;
                        const float w0v = w2[m * LSZ + 3 * c + 0];
                        const float w1v = w2[m * LSZ + 3 * c + 1];
                        const float w2v = w2[m * LSZ + 3 * c + 2];
                        const float sp0 = fmaxf(w0v, 0.f) + log1pf(expf(-fabsf(w0v)));
                        const float sp1 = fmaxf(w1v, 0.f) + log1pf(expf(-fabsf(w1v)));
                        const float sp2 = fmaxf(w2v, 0.f) + log1pf(expf(-fabsf(w2v)));
                        v = (comp == 0) ? 0.5f * (sp0 + sp1)
                          : (comp == 1) ? 0.5f * (sp0 - sp1)
                                        : sp2;
                    }
                } else {
                    const float xv = w2[m * LSZ + (p - 64)];
                    v = 50.0f * (fmaxf(xv, 0.f) + log1pf(expf(-fabsf(xv))));
                }
                vf[ks][j] = (short)f2bf_rne(v);
            }
        }
    }

    // material state (rotated basis)
    float sgu = 0.f, sgv = 0.f, sgw = 0.f, syv = MSY0;  // wave 0
    float hist = 0.f;                                    // wave 1

    __syncthreads();   // chunk 0 visible (full barrier once)

    for (int i = 0; i <= NCHUNK; ++i) {
        if (wv == 0) {
            if (i < NCHUNK) {
                const float* hb = &s_hb[i & 1][0][0];
                float* yb = &s_yf[i & 1][0][0];
                const int off = lane * 4;
                floatx4 ev[TC];
                #pragma unroll
                for (int t = 0; t < TC; ++t)
                    ev[t] = *(const floatx4*)(hb + t * HBS + off);
                #pragma unroll
                for (int t = 0; t < TC; ++t) {
                    const float u = sgu + ev[t].x;
                    const float v = sgv + ev[t].y;
                    const float w = sgw + ev[t].z;
                    const float qq = fmaxf(
                        fmaf(0.25f * u, u, fmaf(0.75f * v, v, (3.0f * w) * w)), 1e-12f);
                    const float rs  = __builtin_amdgcn_rsqf(qq);
                    const float seq = qq * rs;
                    const float pre = AK * syv;
                    const float rr  = fminf(fmaf(pre, rs, BK), 1.0f);
                    sgu = rr * u; sgv = rr * v; sgw = rr * w;
                    syv = fmaxf(syv, fmaf(BK, seq, pre));
                    floatx4 st = {sgu, sgv, sgw, 0.0f};
                    *(floatx4*)(yb + t * YFS + off) = st;
                }
            }
        } else if (wv == 1) {
            if (i < NCHUNK && lane < NCOH) {
                const float* hc = &s_hc[i & 1][0][0];
                float* yb = &s_yf[i & 1][0][0];
                const int off = 2 * lane;
                float2 jv[TC];
                #pragma unroll
                for (int t = 0; t < TC; ++t)
                    jv[t] = *(const float2*)(hc + t * HCS + off);
                #pragma unroll
                for (int t = 0; t < TC; ++t) {
                    const float dn = jv[t].x, ds = jv[t].y;
                    const float dnp = fmaxf(dn, 0.0f);
                    const float lam = __builtin_amdgcn_sqrtf(fmaxf(fmaf(dnp, dnp, ds * ds), 1e-12f));
                    hist = fmaxf(hist, lam);
                    float dmg = (hist - 0.1f) * __builtin_amdgcn_rcpf(hist * 0.9f);
                    dmg = fminf(fmaxf(dmg, 0.0f), 1.0f);
                    const float om = 1.0f - dmg;
                    float2 st;
                    st.x = dn * (dn > 0.0f ? om : 1.0f);   // 50x folded into vf
                    st.y = om * ds;
                    *(float2*)(yb + t * YFS + 256 + off) = st;
                }
            }
        } else if (wv == 2) {
            if (i + 1 < NCHUNK) {
                short8 ax, adh, adl;
                {
                    const unsigned int wc[8] = {rxc[0].x, rxc[0].y, rxc[0].z, rxc[0].w,
                                                rxc[1].x, rxc[1].y, rxc[1].z, rxc[1].w};
                    const unsigned int wp[8] = {rxp[0].x, rxp[0].y, rxp[0].z, rxp[0].w,
                                                rxp[1].x, rxp[1].y, rxp[1].z, rxp[1].w};
                    #pragma unroll
                    for (int j = 0; j < 8; ++j) {
                        unsigned short va = 0, vh = 0, vl = 0;
                        if (q < 2) {
                            const float xc = u2f(wc[j]), xp = u2f(wp[j]);
                            va = f2bf_rne(xc);
                            bfsplit(xc - xp, vh, vl);
                        }
                        ax[j]  = (short)va;
                        adh[j] = (short)vh;
                        adl[j] = (short)vl;
                    }
                }
                if (i + 2 < NCHUNK && q < 2) {
                    const int rowB = (i + 2) * TC + m;
                    const float* xc = x + (xrow + rowB) * FIN + q * 8;
                    const float* xp = x + (xrow + rowB - 1) * FIN + q * 8;
                    rxc[0] = *(const uint4*)xc;  rxc[1] = *(const uint4*)(xc + 4);
                    rxp[0] = *(const uint4*)xp;  rxp[1] = *(const uint4*)(xp + 4);
                }
                float* hbw = &s_hb[(i + 1) & 1][0][0];
                float* hcw = &s_hc[(i + 1) & 1][0][0];
                #pragma unroll
                for (int n = 0; n < 16; ++n) {
                    floatx4 acc = {0.f, 0.f, 0.f, 0.f};
                    if (n < 12) {
                        acc = __builtin_amdgcn_mfma_f32_16x16x32_bf16(adh, w1fdh[n], acc, 0, 0, 0);
                        acc = __builtin_amdgcn_mfma_f32_16x16x32_bf16(adl, w1fdh[n], acc, 0, 0, 0);
                        acc = __builtin_amdgcn_mfma_f32_16x16x32_bf16(adh, w1fdl[n], acc, 0, 0, 0);
                    } else {
                        acc = __builtin_amdgcn_mfma_f32_16x16x32_bf16(ax, w1f4[n - 12], acc, 0, 0, 0);
                    }
                    const int col = n * 16 + m;
                    if (n < 12) {
                        const int cc = col / 3, cm = col - cc * 3;
                        #pragma unroll
                        for (int r = 0; r < 4; ++r)
                            hbw[(q * 4 + r) * HBS + cc * 4 + cm] = acc[r];
                    } else {
                        #pragma unroll
                        for (int r = 0; r < 4; ++r)
                            hcw[(q * 4 + r) * HCS + col - 192] = acc[r];
                    }
                }
            }
        } else {
            if (i >= 1) {
                const int t0 = (i - 1) * TC;
                const float* yb = &s_yf[(i - 1) & 1][0][0];
                floatx4 a0 = {0.f, 0.f, 0.f, 0.f};
                floatx4 a1 = {0.f, 0.f, 0.f, 0.f};
                #pragma unroll
                for (int ks = 0; ks < 10; ++ks) {
                    const float* yp = yb + m * YFS + ks * 32 + q * 8;
                    const floatx4 f0 = *(const floatx4*)yp;
                    const floatx4 f1 = *(const floatx4*)(yp + 4);
                    short8 yf;
                    yf[0] = (short)f2bf_hu(f0.x); yf[1] = (short)f2bf_hu(f0.y);
                    yf[2] = (short)f2bf_hu(f0.z); yf[3] = (short)f2bf_hu(f0.w);
                    yf[4] = (short)f2bf_hu(f1.x); yf[5] = (short)f2bf_hu(f1.y);
                    yf[6] = (short)f2bf_hu(f1.z); yf[7] = (short)f2bf_hu(f1.w);
                    if (ks < 5) a0 = __builtin_amdgcn_mfma_f32_16x16x32_bf16(yf, vf[ks], a0, 0, 0, 0);
                    else        a1 = __builtin_amdgcn_mfma_f32_16x16x32_bf16(yf, vf[ks], a1, 0, 0, 0);
                }
                #pragma unroll
                for (int r = 0; r < 4; ++r)
                    out[(xrow + t0 + q * 4 + r) * FIN + m] = a0[r] + a1[r];
            }
        }
        BARRIER();   // lgkmcnt(0) only — global ops stay in flight
    }
}

extern "C" void kernel_launch(void* const* d_in, const int* in_sizes, int n_in,
                              void* d_out, int out_size, void* d_ws, size_t ws_size,
                              hipStream_t stream) {
    const float* x  = (const float*)d_in[0];   // [256,1024,16] f32
    const float* w1 = (const float*)d_in[1];   // [256,16] f32
    const float* w2 = (const float*)d_in[2];   // [16,256] f32
    float* out = (float*)d_out;                // [256,1024,16] f32
    fused_mat_kernel<<<BATCH, 256, 0, stream>>>(x, w1, w2, out);
}